// Round 3
// baseline (370.255 us; speedup 1.0000x reference)
//
#include <hip/hip_runtime.h>
#include <hip/hip_bf16.h>
#include <math.h>

#define N_NODES 100000
#define N_EDGES 1600000
#define D_FEAT 32
#define D_HID 64
#define D_OUT 64
#define CAP 48        // bucket capacity; deg ~ Poisson(16), P(deg>=48) ~ 1e-11
#define NB_BUCKET 1600   // bucket blocks: 1600*256*4 = 1,638,400 >= N_EDGES
#define NB_NODE   2048   // node-precompute blocks (4 nodes/iter each)
#define NB_AGG    4096

typedef short bf16x8 __attribute__((ext_vector_type(8)));
typedef float f32x4  __attribute__((ext_vector_type(4)));

__device__ inline unsigned short f2bf(float f) {   // RNE f32 -> bf16
    unsigned u = __float_as_uint(f);
    u += 0x7fff + ((u >> 16) & 1);
    return (unsigned short)(u >> 16);
}
__device__ inline float bf2f(unsigned short h) {
    return __uint_as_float(((unsigned)h) << 16);
}

// ---------------------------------------------------------------------------
// Fused prep kernel, block-partitioned:
//   blocks [0, NB_BUCKET):            bucket edges by dst (4 edges/thread,
//                                     int4 edge loads, 4 independent
//                                     atomic->store chains for ILP)
//   blocks [NB_BUCKET, +NB_NODE):     per-node v/q precompute (bf16 store)
// The node path (VALU-bound) overlaps the bucket path (atomic-latency-bound)
// on the same CUs, hiding it.
// ---------------------------------------------------------------------------
__global__ void prep_kernel(const float* __restrict__ x,
                            const float* __restrict__ pos,
                            const float* __restrict__ W1,
                            const float* __restrict__ b1,
                            const int* __restrict__ src,
                            const int* __restrict__ dst,
                            unsigned short* __restrict__ vb,
                            unsigned short* __restrict__ qb,
                            int* __restrict__ cnt,
                            int* __restrict__ slots) {
    if (blockIdx.x < NB_BUCKET) {
        const int e0 = (blockIdx.x * 256 + threadIdx.x) * 4;
        if (e0 < N_EDGES) {                       // N_EDGES % 4 == 0
            int4 s4 = *(const int4*)(src + e0);
            int4 d4 = *(const int4*)(dst + e0);
            int p0 = atomicAdd(&cnt[d4.x], 1);
            int p1 = atomicAdd(&cnt[d4.y], 1);
            int p2 = atomicAdd(&cnt[d4.z], 1);
            int p3 = atomicAdd(&cnt[d4.w], 1);
            if (p0 < CAP) slots[(size_t)d4.x * CAP + p0] = s4.x;
            if (p1 < CAP) slots[(size_t)d4.y * CAP + p1] = s4.y;
            if (p2 < CAP) slots[(size_t)d4.z * CAP + p2] = s4.z;
            if (p3 < CAP) slots[(size_t)d4.w * CAP + p3] = s4.w;
        }
    } else {
        const int lane = threadIdx.x & 63;
        const int sub  = threadIdx.x >> 6;
        const int nb   = blockIdx.x - NB_BUCKET;
        for (int node = nb * 4 + sub; node < N_NODES; node += NB_NODE * 4) {
            float acc = b1[lane];
            const float* xr = x + (size_t)node * D_FEAT;
#pragma unroll
            for (int f = 0; f < D_FEAT; ++f)
                acc = fmaf(xr[f], W1[f * D_HID + lane], acc);

            float qa = 0.0f;
            const float* pr = pos + (size_t)node * 3;
#pragma unroll
            for (int p = 0; p < 3; ++p)
                qa = fmaf(pr[p], W1[(D_FEAT + p) * D_HID + lane], qa);

            vb[(size_t)node * D_HID + lane] = f2bf(acc + qa);
            qb[(size_t)node * D_HID + lane] = f2bf(qa);
        }
    }
}

// ---------------------------------------------------------------------------
// Aggregation: one wave per node per iteration, MFMA layer-2, register max,
// single coalesced store. Slot indices for batch b+1 are loaded before the
// vb-gathers of batch b stall, hiding gather latency.
// ---------------------------------------------------------------------------
__global__ void agg_kernel(const unsigned short* __restrict__ vb,
                           const unsigned short* __restrict__ qb,
                           const float* __restrict__ W2,
                           const float* __restrict__ b2,
                           const int* __restrict__ cnt,
                           const int* __restrict__ slots,
                           float* __restrict__ out) {
    const int lane = threadIdx.x & 63;
    const int quad = lane >> 4;
    const int mrow = lane & 15;
    const int wid    = (blockIdx.x * blockDim.x + threadIdx.x) >> 6;
    const int nwaves = (NB_AGG * 256) >> 6;

    // B fragments: bfrag[t][kh][j] = W2[kh*32 + quad*8 + j][t*16 + mrow]
    bf16x8 bfrag[4][2];
#pragma unroll
    for (int t = 0; t < 4; ++t)
#pragma unroll
        for (int kh = 0; kh < 2; ++kh) {
            bf16x8 f;
#pragma unroll
            for (int j = 0; j < 8; ++j)
                f[j] = (short)f2bf(W2[(kh * 32 + quad * 8 + j) * D_OUT + t * 16 + mrow]);
            bfrag[t][kh] = f;
        }
    float bias[4];
#pragma unroll
    for (int t = 0; t < 4; ++t) bias[t] = b2[t * 16 + mrow];

    for (int i = wid; i < N_NODES; i += nwaves) {
        // q fragment of node i (f32) for both K-halves
        float qf[2][8];
#pragma unroll
        for (int kh = 0; kh < 2; ++kh) {
            bf16x8 qv = *(const bf16x8*)(qb + (size_t)i * D_HID + kh * 32 + quad * 8);
#pragma unroll
            for (int j = 0; j < 8; ++j) qf[kh][j] = bf2f((unsigned short)qv[j]);
        }

        int deg = cnt[i];
        if (deg > CAP) deg = CAP;
        const int rows = deg + 1;                 // + self-loop
        const int nbat = (rows + 15) >> 4;
        const int* srow = slots + (size_t)i * CAP;

        float rmax[4][4];
#pragma unroll
        for (int t = 0; t < 4; ++t)
#pragma unroll
            for (int r = 0; r < 4; ++r) rmax[t][r] = -INFINITY;

        int s_cur = (mrow < deg) ? srow[mrow] : i;
        for (int b = 0; b < nbat; ++b) {
            int s_nxt = i;
            if (b + 1 < nbat) {
                int idx = (b + 1) * 16 + mrow;
                s_nxt = (idx < deg) ? srow[idx] : i;
            }

            bf16x8 afrag[2];
#pragma unroll
            for (int kh = 0; kh < 2; ++kh) {
                bf16x8 vv = *(const bf16x8*)(vb + (size_t)s_cur * D_HID + kh * 32 + quad * 8);
                bf16x8 a;
#pragma unroll
                for (int j = 0; j < 8; j += 2) {
                    float h0 = fmaxf(bf2f((unsigned short)vv[j])     - qf[kh][j],     0.0f);
                    float h1 = fmaxf(bf2f((unsigned short)vv[j + 1]) - qf[kh][j + 1], 0.0f);
                    __hip_bfloat162 p2 = __float22bfloat162_rn(make_float2(h0, h1));
                    a[j]     = (short)__bfloat16_as_ushort(p2.x);
                    a[j + 1] = (short)__bfloat16_as_ushort(p2.y);
                }
                afrag[kh] = a;
            }

            f32x4 acc[4];
#pragma unroll
            for (int t = 0; t < 4; ++t) {
                acc[t] = (f32x4){0.f, 0.f, 0.f, 0.f};
                acc[t] = __builtin_amdgcn_mfma_f32_16x16x32_bf16(afrag[0], bfrag[t][0], acc[t], 0, 0, 0);
                acc[t] = __builtin_amdgcn_mfma_f32_16x16x32_bf16(afrag[1], bfrag[t][1], acc[t], 0, 0, 0);
#pragma unroll
                for (int r = 0; r < 4; ++r)
                    rmax[t][r] = fmaxf(rmax[t][r], acc[t][r]);
            }
            s_cur = s_nxt;
        }

        // reduce over rows: 4 regs within lane, then across quads
        float fin[4];
#pragma unroll
        for (int t = 0; t < 4; ++t) {
            float m = fmaxf(fmaxf(rmax[t][0], rmax[t][1]), fmaxf(rmax[t][2], rmax[t][3]));
            m = fmaxf(m, __shfl_xor(m, 16, 64));
            m = fmaxf(m, __shfl_xor(m, 32, 64));
            fin[t] = m + bias[t];
        }
        float r = (quad == 0) ? fin[0] : (quad == 1) ? fin[1] : (quad == 2) ? fin[2] : fin[3];
        out[(size_t)i * D_OUT + lane] = r;
    }
}

// ---------------------------------------------------------------------------
extern "C" void kernel_launch(void* const* d_in, const int* in_sizes, int n_in,
                              void* d_out, int out_size, void* d_ws, size_t ws_size,
                              hipStream_t stream) {
    const float* x   = (const float*)d_in[0];
    const float* pos = (const float*)d_in[1];
    const int*   ei  = (const int*)d_in[2];   // [2][N_EDGES]: row0=src, row1=dst
    const float* W1  = (const float*)d_in[3];
    const float* b1  = (const float*)d_in[4];
    const float* W2  = (const float*)d_in[5];
    const float* b2  = (const float*)d_in[6];
    float* out = (float*)d_out;

    char* ws = (char*)d_ws;
    unsigned short* vb = (unsigned short*)ws;                          // 12.8 MB
    unsigned short* qb = (unsigned short*)(ws + 12800000);             // 12.8 MB
    int* cnt   = (int*)(ws + 25600000);                                // 0.4 MB
    int* slots = (int*)(ws + 26000000);                                // 19.2 MB

    const int* src = ei;
    const int* dst = ei + N_EDGES;

    hipMemsetAsync(cnt, 0, N_NODES * sizeof(int), stream);
    hipLaunchKernelGGL(prep_kernel, dim3(NB_BUCKET + NB_NODE), dim3(256), 0, stream,
                       x, pos, W1, b1, src, dst, vb, qb, cnt, slots);
    hipLaunchKernelGGL(agg_kernel, dim3(NB_AGG), dim3(256), 0, stream,
                       vb, qb, W2, b2, cnt, slots, out);
}

// Round 4
// 252.009 us; speedup vs baseline: 1.4692x; 1.4692x over previous
//
#include <hip/hip_runtime.h>
#include <hip/hip_bf16.h>
#include <math.h>

#define N_NODES 100000
#define N_EDGES 1600000
#define D_FEAT 32
#define D_HID 64
#define D_OUT 64
#define CAP 48          // per-node slot capacity; deg ~ Poisson(16), safe
#define NPB 64          // nodes per coarse bucket (1<<6)
#define NBKT 1563       // ceil(100000/64)
#define ECAP 1536       // edge capacity per coarse bucket (mean 1024, ~16 sigma)
#define B1 200          // binning blocks; 200 * 8000 = 1.6M edges
#define E_PER_B1 8000

typedef short bf16x8 __attribute__((ext_vector_type(8)));
typedef float f32x4  __attribute__((ext_vector_type(4)));

__device__ inline unsigned short f2bf(float f) {   // RNE f32 -> bf16
    unsigned u = __float_as_uint(f);
    u += 0x7fff + ((u >> 16) & 1);
    return (unsigned short)(u >> 16);
}
__device__ inline float bf2f(unsigned short h) {
    return __uint_as_float(((unsigned)h) << 16);
}

// ---------------------------------------------------------------------------
// Kernel 1: per-node precompute (f32 math, bf16 store)
//   q[n][k] = pos[n] @ W1[32:35];  v[n][k] = b1[k] + x[n] @ W1[:32] + q[n][k]
// per-edge layer-1 output = relu(v[src] - q[dst])
// ---------------------------------------------------------------------------
__global__ void node_kernel(const float* __restrict__ x,
                            const float* __restrict__ pos,
                            const float* __restrict__ W1,
                            const float* __restrict__ b1,
                            unsigned short* __restrict__ vb,
                            unsigned short* __restrict__ qb) {
    const int lane = threadIdx.x & 63;
    const int sub  = threadIdx.x >> 6;
    const int node = blockIdx.x * 4 + sub;
    if (node >= N_NODES) return;

    float acc = b1[lane];
    const float* xr = x + (size_t)node * D_FEAT;
#pragma unroll
    for (int f = 0; f < D_FEAT; ++f)
        acc = fmaf(xr[f], W1[f * D_HID + lane], acc);

    float qa = 0.0f;
    const float* pr = pos + (size_t)node * 3;
#pragma unroll
    for (int p = 0; p < 3; ++p)
        qa = fmaf(pr[p], W1[(D_FEAT + p) * D_HID + lane], qa);

    vb[(size_t)node * D_HID + lane] = f2bf(acc + qa);
    qb[(size_t)node * D_HID + lane] = f2bf(qa);
}

// ---------------------------------------------------------------------------
// Kernel 2: two-phase binning into 1563 coarse buckets of 64 dst-nodes.
// Per block (8000-edge range): LDS histogram -> one global atomicAdd per
// active bucket to reserve a contiguous range -> placement via LDS cursors.
// Appends are contiguous per bucket => dense writes (vs 96 MB of scattered
// 64B-granule writes in the old direct-scatter bucketing).
// Entry packing: (src << 6) | (dst & 63), src < 100000 -> fits u32 easily.
// ---------------------------------------------------------------------------
__global__ void bin_kernel(const int* __restrict__ src,
                           const int* __restrict__ dst,
                           int* __restrict__ gcnt,
                           unsigned int* __restrict__ coarse) {
    __shared__ int hist[NBKT];
    const int tid = threadIdx.x;
    const int e0 = blockIdx.x * E_PER_B1;
    const int e1 = e0 + E_PER_B1;          // 200 * 8000 == N_EDGES exactly

    for (int b = tid; b < NBKT; b += 256) hist[b] = 0;
    __syncthreads();

    for (int e = e0 + tid; e < e1; e += 256)
        atomicAdd(&hist[dst[e] >> 6], 1);
    __syncthreads();

    for (int b = tid; b < NBKT; b += 256) {
        int c = hist[b];
        hist[b] = (c > 0) ? atomicAdd(&gcnt[b], c) : 0;
    }
    __syncthreads();

    for (int e = e0 + tid; e < e1; e += 256) {
        int d = dst[e], s = src[e];
        int b = d >> 6;
        int pos = atomicAdd(&hist[b], 1);
        if (pos < ECAP)
            coarse[(size_t)b * ECAP + pos] = ((unsigned)s << 6) | (unsigned)(d & 63);
    }
}

// ---------------------------------------------------------------------------
// Kernel 3: fused fine-bucketing + per-node MFMA aggregation.
// Block = one coarse bucket (512 thr = 8 waves). Dense read of the bucket's
// edge list; per-node slot lists built in LDS (LDS atomics); then each wave
// runs the per-node loop: A[m][k] = relu(v[src_m][k] - q[i][k]), layer-2 via
// 4x2 mfma_f32_16x16x32_bf16, running register max, one coalesced store.
// Padding rows use src = i (self-loop, idempotent under max).
// ---------------------------------------------------------------------------
__global__ __launch_bounds__(512)
void agg_kernel(const unsigned short* __restrict__ vb,
                const unsigned short* __restrict__ qb,
                const float* __restrict__ W2,
                const float* __restrict__ b2,
                const int* __restrict__ gcnt,
                const unsigned int* __restrict__ coarse,
                float* __restrict__ out) {
    __shared__ int lcnt[NPB];
    __shared__ int lslots[NPB][CAP];

    const int tid  = threadIdx.x;
    const int lane = tid & 63;
    const int wave = tid >> 6;             // 0..7
    const int quad = lane >> 4;
    const int mrow = lane & 15;
    const int bkt  = blockIdx.x;
    const int nbase = bkt << 6;

    // B fragments (global broadcast reads; overlap with LDS binning below)
    bf16x8 bfrag[4][2];
#pragma unroll
    for (int t = 0; t < 4; ++t)
#pragma unroll
        for (int kh = 0; kh < 2; ++kh) {
            bf16x8 f;
#pragma unroll
            for (int j = 0; j < 8; ++j)
                f[j] = (short)f2bf(W2[(kh * 32 + quad * 8 + j) * D_OUT + t * 16 + mrow]);
            bfrag[t][kh] = f;
        }
    float bias[4];
#pragma unroll
    for (int t = 0; t < 4; ++t) bias[t] = b2[t * 16 + mrow];

    // fine bucketing into LDS
    int E_b = gcnt[bkt];
    if (E_b > ECAP) E_b = ECAP;
    for (int i = tid; i < NPB; i += 512) lcnt[i] = 0;
    __syncthreads();
    for (int i = tid; i < E_b; i += 512) {
        unsigned enc = coarse[(size_t)bkt * ECAP + i];
        int local = (int)(enc & 63u);
        int s     = (int)(enc >> 6);
        int p = atomicAdd(&lcnt[local], 1);
        if (p < CAP) lslots[local][p] = s;
    }
    __syncthreads();

    // per-node aggregation, 8 nodes per wave
    for (int ln = wave; ln < NPB; ln += 8) {
        const int node = nbase + ln;
        if (node >= N_NODES) break;

        float qf[2][8];
#pragma unroll
        for (int kh = 0; kh < 2; ++kh) {
            bf16x8 qv = *(const bf16x8*)(qb + (size_t)node * D_HID + kh * 32 + quad * 8);
#pragma unroll
            for (int j = 0; j < 8; ++j) qf[kh][j] = bf2f((unsigned short)qv[j]);
        }

        int deg = lcnt[ln];
        if (deg > CAP) deg = CAP;
        const int rows = deg + 1;              // + self-loop
        const int nbat = (rows + 15) >> 4;

        float rmax[4][4];
#pragma unroll
        for (int t = 0; t < 4; ++t)
#pragma unroll
            for (int r = 0; r < 4; ++r) rmax[t][r] = -INFINITY;

        for (int b = 0; b < nbat; ++b) {
            int idx = b * 16 + mrow;
            int s = (idx < deg) ? lslots[ln][idx] : node;

            bf16x8 afrag[2];
#pragma unroll
            for (int kh = 0; kh < 2; ++kh) {
                bf16x8 vv = *(const bf16x8*)(vb + (size_t)s * D_HID + kh * 32 + quad * 8);
                bf16x8 a;
#pragma unroll
                for (int j = 0; j < 8; j += 2) {
                    float h0 = fmaxf(bf2f((unsigned short)vv[j])     - qf[kh][j],     0.0f);
                    float h1 = fmaxf(bf2f((unsigned short)vv[j + 1]) - qf[kh][j + 1], 0.0f);
                    __hip_bfloat162 p2 = __float22bfloat162_rn(make_float2(h0, h1));
                    a[j]     = (short)__bfloat16_as_ushort(p2.x);
                    a[j + 1] = (short)__bfloat16_as_ushort(p2.y);
                }
                afrag[kh] = a;
            }

            f32x4 acc[4];
#pragma unroll
            for (int t = 0; t < 4; ++t) {
                acc[t] = (f32x4){0.f, 0.f, 0.f, 0.f};
                acc[t] = __builtin_amdgcn_mfma_f32_16x16x32_bf16(afrag[0], bfrag[t][0], acc[t], 0, 0, 0);
                acc[t] = __builtin_amdgcn_mfma_f32_16x16x32_bf16(afrag[1], bfrag[t][1], acc[t], 0, 0, 0);
#pragma unroll
                for (int r = 0; r < 4; ++r)
                    rmax[t][r] = fmaxf(rmax[t][r], acc[t][r]);
            }
        }

        float fin[4];
#pragma unroll
        for (int t = 0; t < 4; ++t) {
            float m = fmaxf(fmaxf(rmax[t][0], rmax[t][1]), fmaxf(rmax[t][2], rmax[t][3]));
            m = fmaxf(m, __shfl_xor(m, 16, 64));
            m = fmaxf(m, __shfl_xor(m, 32, 64));
            fin[t] = m + bias[t];
        }
        float r = (quad == 0) ? fin[0] : (quad == 1) ? fin[1] : (quad == 2) ? fin[2] : fin[3];
        out[(size_t)node * D_OUT + lane] = r;
    }
}

// ---------------------------------------------------------------------------
extern "C" void kernel_launch(void* const* d_in, const int* in_sizes, int n_in,
                              void* d_out, int out_size, void* d_ws, size_t ws_size,
                              hipStream_t stream) {
    const float* x   = (const float*)d_in[0];
    const float* pos = (const float*)d_in[1];
    const int*   ei  = (const int*)d_in[2];   // [2][N_EDGES]: row0=src, row1=dst
    const float* W1  = (const float*)d_in[3];
    const float* b1  = (const float*)d_in[4];
    const float* W2  = (const float*)d_in[5];
    const float* b2  = (const float*)d_in[6];
    float* out = (float*)d_out;

    char* ws = (char*)d_ws;
    unsigned short* vb   = (unsigned short*)ws;                     // 12.8 MB
    unsigned short* qb   = (unsigned short*)(ws + 12800000);        // 12.8 MB
    int*            gcnt = (int*)(ws + 25600000);                   // 6.3 KB
    unsigned int* coarse = (unsigned int*)(ws + 25610240);          // 9.6 MB

    const int* src = ei;
    const int* dst = ei + N_EDGES;

    hipMemsetAsync(gcnt, 0, NBKT * sizeof(int), stream);
    hipLaunchKernelGGL(node_kernel, dim3((N_NODES + 3) / 4), dim3(256), 0, stream,
                       x, pos, W1, b1, vb, qb);
    hipLaunchKernelGGL(bin_kernel, dim3(B1), dim3(256), 0, stream,
                       src, dst, gcnt, coarse);
    hipLaunchKernelGGL(agg_kernel, dim3(NBKT), dim3(512), 0, stream,
                       vb, qb, W2, b2, gcnt, coarse, out);
}

// Round 5
// 209.163 us; speedup vs baseline: 1.7702x; 1.2048x over previous
//
#include <hip/hip_runtime.h>
#include <hip/hip_bf16.h>
#include <math.h>

#define N_NODES 100000
#define N_EDGES 1600000
#define D_FEAT 32
#define D_HID 64
#define D_OUT 64
#define CAP 48          // per-node slot capacity; deg ~ Poisson(16), safe
#define NPB 64          // nodes per coarse bucket (1<<6)
#define NBKT 1563       // ceil(100000/64)
#define ECAP 1536       // edge capacity per coarse bucket (mean 1024, ~16 sigma)
#define B1 256          // binning blocks
#define E_PER_B1 6250   // 256 * 6250 = 1.6M edges exactly
#define NB_NODE 1024    // node-precompute blocks

typedef short bf16x8 __attribute__((ext_vector_type(8)));
typedef float f32x4  __attribute__((ext_vector_type(4)));

__device__ inline unsigned short f2bf(float f) {   // RNE f32 -> bf16
    unsigned u = __float_as_uint(f);
    u += 0x7fff + ((u >> 16) & 1);
    return (unsigned short)(u >> 16);
}
__device__ inline float bf2f(unsigned short h) {
    return __uint_as_float(((unsigned)h) << 16);
}

// ---------------------------------------------------------------------------
// Kernel 1: per-node precompute (f32 math, bf16 store)
//   q[n][k] = pos[n] @ W1[32:35];  v[n][k] = b1[k] + x[n] @ W1[:32] + q[n][k]
// per-edge layer-1 output = relu(v[src] - q[dst]).
// Grid-stride per wave: W1 column (35 regs) + b1 hoisted out of the node
// loop; per node only uniform x/pos s_loads + 35 FMA + 2 coalesced stores.
// ---------------------------------------------------------------------------
__global__ __launch_bounds__(256)
void node_kernel(const float* __restrict__ x,
                 const float* __restrict__ pos,
                 const float* __restrict__ W1,
                 const float* __restrict__ b1,
                 unsigned short* __restrict__ vb,
                 unsigned short* __restrict__ qb) {
    const int lane = threadIdx.x & 63;
    const int wid  = (blockIdx.x * blockDim.x + threadIdx.x) >> 6;
    const int nw   = (NB_NODE * 256) >> 6;

    float w[D_FEAT + 3];
#pragma unroll
    for (int f = 0; f < D_FEAT + 3; ++f)
        w[f] = W1[f * D_HID + lane];
    const float bb = b1[lane];

    for (int node = wid; node < N_NODES; node += nw) {
        const float* xr = x + (size_t)node * D_FEAT;
        float acc = bb;
#pragma unroll
        for (int f = 0; f < D_FEAT; ++f)
            acc = fmaf(xr[f], w[f], acc);

        const float* pr = pos + (size_t)node * 3;
        float qa = 0.0f;
#pragma unroll
        for (int p = 0; p < 3; ++p)
            qa = fmaf(pr[p], w[D_FEAT + p], qa);

        vb[(size_t)node * D_HID + lane] = f2bf(acc + qa);
        qb[(size_t)node * D_HID + lane] = f2bf(qa);
    }
}

// ---------------------------------------------------------------------------
// Kernel 2: two-phase binning into 1563 coarse buckets of 64 dst-nodes.
// Per block: LDS histogram -> one global atomicAdd per active bucket to
// reserve a contiguous range -> placement via LDS cursors (dense appends).
// 1024 threads/block for latency hiding; 256 blocks keeps per-block-per-
// bucket appends at ~4 entries (~16B/64B line) to bound write amplification.
// Entry packing: (src << 6) | (dst & 63).
// ---------------------------------------------------------------------------
__global__ __launch_bounds__(1024)
void bin_kernel(const int* __restrict__ src,
                const int* __restrict__ dst,
                int* __restrict__ gcnt,
                unsigned int* __restrict__ coarse) {
    __shared__ int hist[NBKT];
    const int tid = threadIdx.x;
    const int e0 = blockIdx.x * E_PER_B1;
    const int e1 = e0 + E_PER_B1;          // 256 * 6250 == N_EDGES exactly

    for (int b = tid; b < NBKT; b += 1024) hist[b] = 0;
    __syncthreads();

    for (int e = e0 + tid; e < e1; e += 1024)
        atomicAdd(&hist[dst[e] >> 6], 1);
    __syncthreads();

    for (int b = tid; b < NBKT; b += 1024) {
        int c = hist[b];
        hist[b] = (c > 0) ? atomicAdd(&gcnt[b], c) : 0;
    }
    __syncthreads();

    for (int e = e0 + tid; e < e1; e += 1024) {
        int d = dst[e], s = src[e];
        int b = d >> 6;
        int pos = atomicAdd(&hist[b], 1);
        if (pos < ECAP)
            coarse[(size_t)b * ECAP + pos] = ((unsigned)s << 6) | (unsigned)(d & 63);
    }
}

// ---------------------------------------------------------------------------
// Kernel 3: fused fine-bucketing + per-node MFMA aggregation.
// Block = one coarse bucket, 256 threads = 4 waves (fine-grained packing for
// occupancy). Dense read of the bucket's edge list; per-node slot lists in
// LDS; each wave aggregates 16 nodes: A[m][k] = relu(v[src_m][k] - q[i][k]),
// layer-2 via 4x2 mfma_f32_16x16x32_bf16, register max, coalesced store.
// Padding rows use src = i (self-loop, idempotent under max).
// ---------------------------------------------------------------------------
__global__ __launch_bounds__(256)
void agg_kernel(const unsigned short* __restrict__ vb,
                const unsigned short* __restrict__ qb,
                const float* __restrict__ W2,
                const float* __restrict__ b2,
                const int* __restrict__ gcnt,
                const unsigned int* __restrict__ coarse,
                float* __restrict__ out) {
    __shared__ int lcnt[NPB];
    __shared__ int lslots[NPB][CAP];

    const int tid  = threadIdx.x;
    const int lane = tid & 63;
    const int wave = tid >> 6;             // 0..3
    const int quad = lane >> 4;
    const int mrow = lane & 15;
    const int bkt  = blockIdx.x;
    const int nbase = bkt << 6;

    // B fragments: bfrag[t][kh][j] = W2[kh*32 + quad*8 + j][t*16 + mrow]
    bf16x8 bfrag[4][2];
#pragma unroll
    for (int t = 0; t < 4; ++t)
#pragma unroll
        for (int kh = 0; kh < 2; ++kh) {
            bf16x8 f;
#pragma unroll
            for (int j = 0; j < 8; ++j)
                f[j] = (short)f2bf(W2[(kh * 32 + quad * 8 + j) * D_OUT + t * 16 + mrow]);
            bfrag[t][kh] = f;
        }
    float bias[4];
#pragma unroll
    for (int t = 0; t < 4; ++t) bias[t] = b2[t * 16 + mrow];

    // fine bucketing into LDS
    int E_b = gcnt[bkt];
    if (E_b > ECAP) E_b = ECAP;
    for (int i = tid; i < NPB; i += 256) lcnt[i] = 0;
    __syncthreads();
    for (int i = tid; i < E_b; i += 256) {
        unsigned enc = coarse[(size_t)bkt * ECAP + i];
        int local = (int)(enc & 63u);
        int s     = (int)(enc >> 6);
        int p = atomicAdd(&lcnt[local], 1);
        if (p < CAP) lslots[local][p] = s;
    }
    __syncthreads();

    // per-node aggregation, 16 nodes per wave
    for (int ln = wave; ln < NPB; ln += 4) {
        const int node = nbase + ln;
        if (node >= N_NODES) break;

        float qf[2][8];
#pragma unroll
        for (int kh = 0; kh < 2; ++kh) {
            bf16x8 qv = *(const bf16x8*)(qb + (size_t)node * D_HID + kh * 32 + quad * 8);
#pragma unroll
            for (int j = 0; j < 8; ++j) qf[kh][j] = bf2f((unsigned short)qv[j]);
        }

        int deg = lcnt[ln];
        if (deg > CAP) deg = CAP;
        const int rows = deg + 1;              // + self-loop
        const int nbat = (rows + 15) >> 4;

        float rmax[4][4];
#pragma unroll
        for (int t = 0; t < 4; ++t)
#pragma unroll
            for (int r = 0; r < 4; ++r) rmax[t][r] = -INFINITY;

        for (int b = 0; b < nbat; ++b) {
            int idx = b * 16 + mrow;
            int idxc = (idx < CAP) ? idx : (CAP - 1);    // clamp LDS read
            int s = (idx < deg) ? lslots[ln][idxc] : node;

            bf16x8 afrag[2];
#pragma unroll
            for (int kh = 0; kh < 2; ++kh) {
                bf16x8 vv = *(const bf16x8*)(vb + (size_t)s * D_HID + kh * 32 + quad * 8);
                bf16x8 a;
#pragma unroll
                for (int j = 0; j < 8; j += 2) {
                    float h0 = fmaxf(bf2f((unsigned short)vv[j])     - qf[kh][j],     0.0f);
                    float h1 = fmaxf(bf2f((unsigned short)vv[j + 1]) - qf[kh][j + 1], 0.0f);
                    __hip_bfloat162 p2 = __float22bfloat162_rn(make_float2(h0, h1));
                    a[j]     = (short)__bfloat16_as_ushort(p2.x);
                    a[j + 1] = (short)__bfloat16_as_ushort(p2.y);
                }
                afrag[kh] = a;
            }

            f32x4 acc[4];
#pragma unroll
            for (int t = 0; t < 4; ++t) {
                acc[t] = (f32x4){0.f, 0.f, 0.f, 0.f};
                acc[t] = __builtin_amdgcn_mfma_f32_16x16x32_bf16(afrag[0], bfrag[t][0], acc[t], 0, 0, 0);
                acc[t] = __builtin_amdgcn_mfma_f32_16x16x32_bf16(afrag[1], bfrag[t][1], acc[t], 0, 0, 0);
#pragma unroll
                for (int r = 0; r < 4; ++r)
                    rmax[t][r] = fmaxf(rmax[t][r], acc[t][r]);
            }
        }

        float fin[4];
#pragma unroll
        for (int t = 0; t < 4; ++t) {
            float m = fmaxf(fmaxf(rmax[t][0], rmax[t][1]), fmaxf(rmax[t][2], rmax[t][3]));
            m = fmaxf(m, __shfl_xor(m, 16, 64));
            m = fmaxf(m, __shfl_xor(m, 32, 64));
            fin[t] = m + bias[t];
        }
        float r = (quad == 0) ? fin[0] : (quad == 1) ? fin[1] : (quad == 2) ? fin[2] : fin[3];
        out[(size_t)node * D_OUT + lane] = r;
    }
}

// ---------------------------------------------------------------------------
extern "C" void kernel_launch(void* const* d_in, const int* in_sizes, int n_in,
                              void* d_out, int out_size, void* d_ws, size_t ws_size,
                              hipStream_t stream) {
    const float* x   = (const float*)d_in[0];
    const float* pos = (const float*)d_in[1];
    const int*   ei  = (const int*)d_in[2];   // [2][N_EDGES]: row0=src, row1=dst
    const float* W1  = (const float*)d_in[3];
    const float* b1  = (const float*)d_in[4];
    const float* W2  = (const float*)d_in[5];
    const float* b2  = (const float*)d_in[6];
    float* out = (float*)d_out;

    char* ws = (char*)d_ws;
    unsigned short* vb   = (unsigned short*)ws;                     // 12.8 MB
    unsigned short* qb   = (unsigned short*)(ws + 12800000);        // 12.8 MB
    int*            gcnt = (int*)(ws + 25600000);                   // 6.3 KB
    unsigned int* coarse = (unsigned int*)(ws + 25610240);          // 9.6 MB

    const int* src = ei;
    const int* dst = ei + N_EDGES;

    hipMemsetAsync(gcnt, 0, NBKT * sizeof(int), stream);
    hipLaunchKernelGGL(bin_kernel, dim3(B1), dim3(1024), 0, stream,
                       src, dst, gcnt, coarse);
    hipLaunchKernelGGL(node_kernel, dim3(NB_NODE), dim3(256), 0, stream,
                       x, pos, W1, b1, vb, qb);
    hipLaunchKernelGGL(agg_kernel, dim3(NBKT), dim3(256), 0, stream,
                       vb, qb, W2, b2, gcnt, coarse, out);
}